// Round 1
// baseline (1285.778 us; speedup 1.0000x reference)
//
#include <hip/hip_runtime.h>
#include <hip/hip_bf16.h>

// Problem constants (match reference)
#define NB 65536   // batch
#define NP 1024    // prototypes
#define ND 512     // embed dim

// ---------------------------------------------------------------------------
// Kernel 1: per-centroid inverse norm: 1 / max(||c_p||, 1e-12)
// One wave per centroid row; 4 waves per block.
// ---------------------------------------------------------------------------
__global__ void centroid_rnorm_kernel(const float* __restrict__ cent,
                                      float* __restrict__ rnorm) {
    const int row  = blockIdx.x * 4 + (threadIdx.x >> 6);
    const int lane = threadIdx.x & 63;
    const float4* cr = (const float4*)(cent + (size_t)row * ND);
    float4 a = cr[2 * lane];
    float4 b = cr[2 * lane + 1];
    float s = a.x * a.x + a.y * a.y + a.z * a.z + a.w * a.w
            + b.x * b.x + b.y * b.y + b.z * b.z + b.w * b.w;
#pragma unroll
    for (int off = 32; off > 0; off >>= 1)
        s += __shfl_down(s, off, 64);
    if (lane == 0)
        rnorm[row] = 1.0f / fmaxf(sqrtf(s), 1e-12f);
}

// ---------------------------------------------------------------------------
// Kernel 2: fused fp32 GEMM + row argmax.
// Block: 256 threads = (ty 0..7) x (tx 0..31). Block tile: 64 queries x 256
// centroids per chunk (4 chunks cover P=1024). Per-thread 8x8 accumulators.
// LDS tiles [row][k] padded to stride 36 floats (16B-aligned rows; Q reads
// broadcast, C reads at worst 4-way conflict = 1.58x, free-ish).
// Epilogue scales by 1/||c_p|| and tracks running (max, argmax) with
// numpy-compatible first-max tie-breaking.
// ---------------------------------------------------------------------------
#define KC 32
#define LDS_STRIDE 36
#define CHUNK 256
#define QT 64

__launch_bounds__(256, 2)
__global__ void gemm_argmax_kernel(const float* __restrict__ Q,
                                   const float* __restrict__ C,
                                   const float* __restrict__ rnorm,
                                   float* __restrict__ assign_out,
                                   int* __restrict__ idx_out) {
    __shared__ float q_s[QT * LDS_STRIDE];      //  9216 B
    __shared__ float c_s[CHUNK * LDS_STRIDE];   // 36864 B
    const int tid   = threadIdx.x;
    const int tx    = tid & 31;   // centroid lane: owns c = tx + 32*j
    const int ty    = tid >> 5;   // query group: owns q = 8*ty + i
    const int qbase = blockIdx.x * QT;

    float best[8];
    int   besti[8];
#pragma unroll
    for (int i = 0; i < 8; ++i) { best[i] = -3.0e38f; besti[i] = 0; }

    for (int chunk = 0; chunk < NP / CHUNK; ++chunk) {
        float acc[8][8];
#pragma unroll
        for (int i = 0; i < 8; ++i)
#pragma unroll
            for (int j = 0; j < 8; ++j) acc[i][j] = 0.0f;

        for (int k0 = 0; k0 < ND; k0 += KC) {
            __syncthreads();  // protect LDS from previous iteration's readers
            // Stage Q tile: 64 rows x 32 k = 512 float4, 2 per thread.
#pragma unroll
            for (int r = 0; r < 2; ++r) {
                int f = tid + 256 * r;
                int row = f >> 3, c4 = (f & 7) << 2;
                float4 v = *(const float4*)(Q + (size_t)(qbase + row) * ND + k0 + c4);
                *(float4*)(q_s + row * LDS_STRIDE + c4) = v;
            }
            // Stage C tile: 256 rows x 32 k = 2048 float4, 8 per thread.
#pragma unroll
            for (int r = 0; r < 8; ++r) {
                int f = tid + 256 * r;
                int row = f >> 3, c4 = (f & 7) << 2;
                float4 v = *(const float4*)(C + (size_t)(chunk * CHUNK + row) * ND + k0 + c4);
                *(float4*)(c_s + row * LDS_STRIDE + c4) = v;
            }
            __syncthreads();

            for (int kk = 0; kk < KC; kk += 4) {
                float4 qv[8], cv[8];
#pragma unroll
                for (int i = 0; i < 8; ++i)
                    qv[i] = *(const float4*)(q_s + (8 * ty + i) * LDS_STRIDE + kk);
#pragma unroll
                for (int j = 0; j < 8; ++j)
                    cv[j] = *(const float4*)(c_s + (tx + 32 * j) * LDS_STRIDE + kk);
#pragma unroll
                for (int i = 0; i < 8; ++i)
#pragma unroll
                    for (int j = 0; j < 8; ++j) {
                        acc[i][j] = fmaf(qv[i].x, cv[j].x, acc[i][j]);
                        acc[i][j] = fmaf(qv[i].y, cv[j].y, acc[i][j]);
                        acc[i][j] = fmaf(qv[i].z, cv[j].z, acc[i][j]);
                        acc[i][j] = fmaf(qv[i].w, cv[j].w, acc[i][j]);
                    }
            }
        }

        // Epilogue for this centroid chunk: scale by 1/||c||, update argmax.
        float rn[8];
#pragma unroll
        for (int j = 0; j < 8; ++j) rn[j] = rnorm[chunk * CHUNK + tx + 32 * j];
#pragma unroll
        for (int i = 0; i < 8; ++i)
#pragma unroll
            for (int j = 0; j < 8; ++j) {
                float v  = acc[i][j] * rn[j];
                int   ci = chunk * CHUNK + tx + 32 * j;
                if (v > best[i] || (v == best[i] && ci < besti[i])) {
                    best[i] = v; besti[i] = ci;
                }
            }
    }

    // Cross-thread reduction over the 32 tx lanes per query (via LDS reuse).
    __syncthreads();
    float* rv = c_s;                   // 64*32 floats
    int*   ri = (int*)(c_s + 2048);    // 64*32 ints, no overlap
#pragma unroll
    for (int i = 0; i < 8; ++i) {
        rv[(8 * ty + i) * 32 + tx] = best[i];
        ri[(8 * ty + i) * 32 + tx] = besti[i];
    }
    __syncthreads();
    if (tid < 64) {
        float bv = -3.0e38f; int bi = NP;
        for (int t = 0; t < 32; ++t) {
            float v = rv[tid * 32 + t];
            int   c = ri[tid * 32 + t];
            if (v > bv || (v == bv && c < bi)) { bv = v; bi = c; }
        }
        int q = qbase + tid;
        assign_out[q] = (float)bi;  // output dtype is fp32
        idx_out[q]    = bi;
    }
}

// ---------------------------------------------------------------------------
// Kernel 3: context gather (raw centroid row) + one-hot scatter.
// Two queries per 256-thread block; 128 threads copy 512 floats as float4.
// ---------------------------------------------------------------------------
__global__ void scatter_gather_kernel(const float* __restrict__ cent,
                                      const int* __restrict__ idx,
                                      float* __restrict__ ctx,
                                      float* __restrict__ routing) {
    const int q    = blockIdx.x * 2 + (threadIdx.x >> 7);
    const int lane = threadIdx.x & 127;
    const int ci   = idx[q];
    const float4* src = (const float4*)(cent + (size_t)ci * ND);
    float4*       dst = (float4*)(ctx + (size_t)q * ND);
    dst[lane] = src[lane];
    if (lane == 0) routing[(size_t)q * NP + ci] = 1.0f;
}

// ---------------------------------------------------------------------------
extern "C" void kernel_launch(void* const* d_in, const int* in_sizes, int n_in,
                              void* d_out, int out_size, void* d_ws, size_t ws_size,
                              hipStream_t stream) {
    const float* query = (const float*)d_in[0];   // (B, D) fp32
    const float* cent  = (const float*)d_in[1];   // (P, D) fp32

    float* out        = (float*)d_out;
    float* ctx        = out;                               // B*D
    float* assign_out = out + (size_t)NB * ND;             // B
    float* routing    = assign_out + NB;                   // B*P

    float* rnorm = (float*)d_ws;            // 1024 floats
    int*   idx   = (int*)d_ws + 1024;       // 65536 ints

    // Zero the one-hot region (re-poisoned to 0xAA before every timed call).
    hipMemsetAsync(routing, 0, (size_t)NB * NP * sizeof(float), stream);

    centroid_rnorm_kernel<<<NP / 4, 256, 0, stream>>>(cent, rnorm);
    gemm_argmax_kernel<<<NB / QT, 256, 0, stream>>>(query, cent, rnorm,
                                                    assign_out, idx);
    scatter_gather_kernel<<<NB / 2, 256, 0, stream>>>(cent, idx, ctx, routing);
}

// Round 2
// 1050.956 us; speedup vs baseline: 1.2234x; 1.2234x over previous
//
#include <hip/hip_runtime.h>
#include <hip/hip_bf16.h>
#include <climits>
#include <cstdint>

#define NB 65536   // batch
#define NP 1024    // prototypes
#define ND 512     // embed dim

#define MARGIN 4e-4f   // flag rows whose approx top-2 gap is below this (scaled units)

typedef _Float16 f16x8 __attribute__((ext_vector_type(8)));
typedef float    f32x4 __attribute__((ext_vector_type(4)));

__device__ inline void load_lds16(const void* g, void* l) {
    __builtin_amdgcn_global_load_lds(
        (const __attribute__((address_space(1))) void*)g,
        (__attribute__((address_space(3))) void*)l, 16, 0, 0);
}

// ---------------------------------------------------------------------------
// rnorm[p] = 1 / max(||c_p||, 1e-12). One wave per row.
// ---------------------------------------------------------------------------
__global__ void centroid_rnorm_kernel(const float* __restrict__ cent,
                                      float* __restrict__ rnorm) {
    const int row  = blockIdx.x * 4 + (threadIdx.x >> 6);
    const int lane = threadIdx.x & 63;
    const float4* cr = (const float4*)(cent + (size_t)row * ND);
    float4 a = cr[2 * lane];
    float4 b = cr[2 * lane + 1];
    float s = a.x * a.x + a.y * a.y + a.z * a.z + a.w * a.w
            + b.x * b.x + b.y * b.y + b.z * b.z + b.w * b.w;
#pragma unroll
    for (int off = 32; off > 0; off >>= 1)
        s += __shfl_down(s, off, 64);
    if (lane == 0)
        rnorm[row] = 1.0f / fmaxf(sqrtf(s), 1e-12f);
}

// ---------------------------------------------------------------------------
// fp32 -> f16 hi/lo split converters.
// Qp layout: [row][0:512]=hi, [512:1024]=lo    (65536 x 1024 f16)
// Cp layout: [row][0:512]=hi, [512:1024]=hi, [1024:1536]=lo  (1024 x 1536 f16)
// ---------------------------------------------------------------------------
__global__ void convertQ_kernel(const float* __restrict__ Q,
                                _Float16* __restrict__ Qp) {
    const size_t t = (size_t)blockIdx.x * 256 + threadIdx.x;  // 8 elems/thread
    const size_t base = t * 8;
    const int row = (int)(base >> 9), c = (int)(base & 511);
    const float4* s = (const float4*)(Q + base);
    float4 x0 = s[0], x1 = s[1];
    float xs[8] = {x0.x, x0.y, x0.z, x0.w, x1.x, x1.y, x1.z, x1.w};
    f16x8 hi, lo;
#pragma unroll
    for (int i = 0; i < 8; ++i) {
        _Float16 h = (_Float16)xs[i];
        hi[i] = h;
        lo[i] = (_Float16)(xs[i] - (float)h);
    }
    *(f16x8*)(Qp + (size_t)row * 1024 + c)       = hi;
    *(f16x8*)(Qp + (size_t)row * 1024 + 512 + c) = lo;
}

__global__ void convertC_kernel(const float* __restrict__ C,
                                _Float16* __restrict__ Cp) {
    const size_t t = (size_t)blockIdx.x * 256 + threadIdx.x;
    const size_t base = t * 8;
    const int row = (int)(base >> 9), c = (int)(base & 511);
    const float4* s = (const float4*)(C + base);
    float4 x0 = s[0], x1 = s[1];
    float xs[8] = {x0.x, x0.y, x0.z, x0.w, x1.x, x1.y, x1.z, x1.w};
    f16x8 hi, lo;
#pragma unroll
    for (int i = 0; i < 8; ++i) {
        _Float16 h = (_Float16)xs[i];
        hi[i] = h;
        lo[i] = (_Float16)(xs[i] - (float)h);
    }
    *(f16x8*)(Cp + (size_t)row * 1536 + c)        = hi;
    *(f16x8*)(Cp + (size_t)row * 1536 + 512 + c)  = hi;
    *(f16x8*)(Cp + (size_t)row * 1536 + 1024 + c) = lo;
}

// ---------------------------------------------------------------------------
// MFMA GEMM over virtual K=1536 (= qh.ch + ql.ch + qh.cl) fused with per-row
// top-2 tracking (scaled by rnorm). 128x128 block tile, 4 waves of 64x64
// (4x4 MFMA 16x16x32 f16), BK=64, global_load_lds width-16 staging.
// Grid 4096 = 512 m-blocks x 8 n-blocks, swizzled so the 8 n-blocks of an
// m-tile are consecutive on one XCD (A tile fetched once from HBM).
// Writes per (row, n-block): partial {v1, i1, v2}.
// ---------------------------------------------------------------------------
__launch_bounds__(256)
__global__ void gemm_top2_kernel(const _Float16* __restrict__ Qp,
                                 const _Float16* __restrict__ Cp,
                                 const float* __restrict__ rnorm,
                                 float* __restrict__ pv1,
                                 int*   __restrict__ pi1,
                                 float* __restrict__ pv2) {
    __shared__ __align__(16) _Float16 a_s[128 * 64];  // 16 KB
    __shared__ __align__(16) _Float16 b_s[128 * 64];  // 16 KB

    const int tid  = threadIdx.x;
    const int wave = tid >> 6, lane = tid & 63;

    // XCD-contiguous swizzle: xcd = bid&7 sees all 8 n for each of its m's.
    const int bid = blockIdx.x;
    const int x = bid & 7, j = bid >> 3;
    const int nb = j & 7;
    const int mb = (j >> 3) * 8 + x;
    const int mbase = mb * 128, nbase = nb * 128;

    const int wm = wave >> 1, wn = wave & 1;
    const int quad = lane >> 4, l15 = lane & 15;

    f32x4 acc[4][4] = {};

    // staging addressing: lane l covers row (seg*8 + l>>3), col (l&7)*8
    const _Float16* aBase = Qp + (size_t)(mbase + (lane >> 3)) * 1024 + ((lane & 7) << 3);
    const _Float16* bBase = Cp + (size_t)(nbase + (lane >> 3)) * 1536 + ((lane & 7) << 3);
    _Float16* aDst = a_s + wave * 512;
    _Float16* bDst = b_s + wave * 512;

    for (int kc = 0; kc < 24; ++kc) {
        const int kv = kc << 6;
        const int kA = (kv < 1024) ? kv : (kv - 1024);  // [qh|ql|qh] virtual
        __syncthreads();
#pragma unroll
        for (int it = 0; it < 4; ++it) {
            const int s8 = (it * 4 + wave) * 8;
            load_lds16(aBase + (size_t)s8 * 1024 + kA, aDst + it * 2048);
            load_lds16(bBase + (size_t)s8 * 1536 + kv, bDst + it * 2048);
        }
        __syncthreads();
#pragma unroll
        for (int kk = 0; kk < 64; kk += 32) {
            f16x8 af[4], bf[4];
#pragma unroll
            for (int mt = 0; mt < 4; ++mt)
                af[mt] = *(const f16x8*)&a_s[(wm * 64 + mt * 16 + l15) * 64 + kk + quad * 8];
#pragma unroll
            for (int nt = 0; nt < 4; ++nt)
                bf[nt] = *(const f16x8*)&b_s[(wn * 64 + nt * 16 + l15) * 64 + kk + quad * 8];
#pragma unroll
            for (int mt = 0; mt < 4; ++mt)
#pragma unroll
                for (int nt = 0; nt < 4; ++nt)
                    acc[mt][nt] = __builtin_amdgcn_mfma_f32_16x16x32_f16(
                        af[mt], bf[nt], acc[mt][nt], 0, 0, 0);
        }
    }

    // ---- epilogue: scale + per-row top-2 over this block's 128 cols ----
    __syncthreads();
    float* lv1 = (float*)a_s;          // [128][2]
    int*   li1 = (int*)(lv1 + 256);    // [128][2]
    float* lv2 = (float*)(li1 + 256);  // [128][2]

    float rn[4];
#pragma unroll
    for (int nt = 0; nt < 4; ++nt)
        rn[nt] = rnorm[nbase + wn * 64 + nt * 16 + l15];

#pragma unroll
    for (int mt = 0; mt < 4; ++mt) {
#pragma unroll
        for (int r = 0; r < 4; ++r) {
            float v1 = -3.0e38f, v2 = -3.0e38f; int i1 = INT_MAX;
#pragma unroll
            for (int nt = 0; nt < 4; ++nt) {
                float v = acc[mt][nt][r] * rn[nt];
                int   c = nbase + wn * 64 + nt * 16 + l15;
                if (v > v1) { v2 = v1; v1 = v; i1 = c; }
                else { if (v > v2) v2 = v; if (v == v1 && c < i1) i1 = c; }
            }
            // butterfly over the 16 column-lanes (same rows)
#pragma unroll
            for (int mask = 1; mask < 16; mask <<= 1) {
                float ov1 = __shfl_xor(v1, mask, 64);
                int   oi1 = __shfl_xor(i1, mask, 64);
                float ov2 = __shfl_xor(v2, mask, 64);
                if (ov1 > v1) { v2 = fmaxf(v1, ov2); v1 = ov1; i1 = oi1; }
                else if (ov1 == v1) { v2 = v1; i1 = min(i1, oi1); }
                else { v2 = fmaxf(v2, ov1); }
            }
            if (l15 == 0) {
                int row = wm * 64 + mt * 16 + quad * 4 + r;
                lv1[row * 2 + wn] = v1;
                li1[row * 2 + wn] = i1;
                lv2[row * 2 + wn] = v2;
            }
        }
    }
    __syncthreads();
    if (tid < 128) {
        float v1 = lv1[tid * 2],     v2 = lv2[tid * 2];     int i1 = li1[tid * 2];
        float w1 = lv1[tid * 2 + 1], w2 = lv2[tid * 2 + 1]; int j1 = li1[tid * 2 + 1];
        float V1, V2; int I1;
        if (w1 > v1)       { V1 = w1; I1 = j1; V2 = fmaxf(v1, w2); }
        else if (w1 == v1) { V1 = v1; I1 = min(i1, j1); V2 = v1; }
        else               { V1 = v1; I1 = i1; V2 = fmaxf(v2, w1); }
        const size_t g = (size_t)(mbase + tid) * 8 + nb;
        pv1[g] = V1; pi1[g] = I1; pv2[g] = V2;
    }
}

// ---------------------------------------------------------------------------
// Merge the 8 per-chunk partials per row; write argmax; flag near-ties.
// ---------------------------------------------------------------------------
__global__ void merge_kernel(const float* __restrict__ pv1,
                             const int*   __restrict__ pi1,
                             const float* __restrict__ pv2,
                             float* __restrict__ assign_out,
                             int* __restrict__ rlist, int* __restrict__ rcount) {
    const int row = blockIdx.x * 256 + threadIdx.x;
    float v1 = -3.0e38f, v2 = -3.0e38f; int i1 = INT_MAX;
    const size_t b = (size_t)row * 8;
#pragma unroll
    for (int n = 0; n < 8; ++n) {
        float a1 = pv1[b + n]; int ai = pi1[b + n]; float a2 = pv2[b + n];
        if (a1 > v1)       { v2 = fmaxf(v1, a2); v1 = a1; i1 = ai; }
        else if (a1 == v1) { v2 = v1; i1 = min(i1, ai); }
        else               { v2 = fmaxf(v2, a1); }
    }
    assign_out[row] = (float)i1;
    if (v1 - v2 < MARGIN) {
        int p = atomicAdd(rcount, 1);
        rlist[p] = row;
    }
}

// ---------------------------------------------------------------------------
// Exact fp32 recompute for flagged rows (full 1024 centroids per row).
// ---------------------------------------------------------------------------
__launch_bounds__(256)
__global__ void refine_kernel(const float* __restrict__ Q,
                              const float* __restrict__ C,
                              const float* __restrict__ rnorm,
                              const int* __restrict__ rlist,
                              const int* __restrict__ rcount,
                              float* __restrict__ assign_out) {
    __shared__ float4 qs[128];
    __shared__ float wv[4];
    __shared__ int   wi[4];
    const int n = *rcount;
    const int wave = threadIdx.x >> 6, lane = threadIdx.x & 63;
    for (int it = blockIdx.x; it < n; it += gridDim.x) {
        const int row = rlist[it];
        __syncthreads();
        if (threadIdx.x < 128)
            qs[threadIdx.x] = ((const float4*)(Q + (size_t)row * ND))[threadIdx.x];
        __syncthreads();
        float best = -3.0e38f; int bi = INT_MAX;
        for (int p = wave; p < NP; p += 4) {
            const float4* cr = (const float4*)(C + (size_t)p * ND);
            float4 a = qs[lane],      b = cr[lane];
            float4 a2 = qs[lane + 64], b2 = cr[lane + 64];
            float s = a.x * b.x + a.y * b.y + a.z * b.z + a.w * b.w
                    + a2.x * b2.x + a2.y * b2.y + a2.z * b2.z + a2.w * b2.w;
#pragma unroll
            for (int m = 1; m < 64; m <<= 1) s += __shfl_xor(s, m, 64);
            s *= rnorm[p];
            if (s > best) { best = s; bi = p; }  // ascending p: first-max wins
        }
        if (lane == 0) { wv[wave] = best; wi[wave] = bi; }
        __syncthreads();
        if (threadIdx.x == 0) {
            float bv = wv[0]; int b0 = wi[0];
            for (int w = 1; w < 4; ++w)
                if (wv[w] > bv || (wv[w] == bv && wi[w] < b0)) { bv = wv[w]; b0 = wi[w]; }
            assign_out[row] = (float)b0;
        }
    }
}

// ---------------------------------------------------------------------------
// ctx gather + routing row write (zeros fused with the single 1.0).
// Covers the entire routing region, so no separate memset is needed.
// ---------------------------------------------------------------------------
__global__ void scatter_kernel(const float* __restrict__ cent,
                               const float* __restrict__ assign,
                               float* __restrict__ ctx,
                               float* __restrict__ routing) {
    const int q    = blockIdx.x * 2 + (threadIdx.x >> 7);
    const int lane = threadIdx.x & 127;
    const int ci   = (int)assign[q];
    const float4* src = (const float4*)(cent + (size_t)ci * ND);
    ((float4*)(ctx + (size_t)q * ND))[lane] = src[lane];
    float4 z1 = {0.f, 0.f, 0.f, 0.f};
    float4 z2 = {0.f, 0.f, 0.f, 0.f};
    if ((ci >> 2) == lane)        ((float*)&z1)[ci & 3] = 1.0f;
    if ((ci >> 2) == lane + 128)  ((float*)&z2)[ci & 3] = 1.0f;
    float4* rr = (float4*)(routing + (size_t)q * NP);
    rr[lane]       = z1;
    rr[lane + 128] = z2;
}

// ---------------------------------------------------------------------------
extern "C" void kernel_launch(void* const* d_in, const int* in_sizes, int n_in,
                              void* d_out, int out_size, void* d_ws, size_t ws_size,
                              hipStream_t stream) {
    const float* query = (const float*)d_in[0];   // (B, D) fp32
    const float* cent  = (const float*)d_in[1];   // (P, D) fp32

    float* out        = (float*)d_out;
    float* ctx        = out;                       // B*D
    float* assign_out = out + (size_t)NB * ND;     // B
    float* routing    = assign_out + NB;           // B*P (268 MB)

    // All bulky scratch lives inside the routing region; it is fully
    // overwritten by scatter_kernel at the end. d_ws is unused.
    char* scratch = (char*)routing;
    _Float16* Qp    = (_Float16*)(scratch);                       // 134,217,728 B
    _Float16* Cp    = (_Float16*)(scratch + 134217728);           //   3,145,728 B
    float*    rnorm = (float*)   (scratch + 137363456);           //       4,096 B
    float*    pv1   = (float*)   (scratch + 137367552);           //   2,097,152 B
    int*      pi1   = (int*)     (scratch + 139464704);           //   2,097,152 B
    float*    pv2   = (float*)   (scratch + 141561856);           //   2,097,152 B
    int*      rlist = (int*)     (scratch + 143659008);           //     262,144 B
    int*      rcount= (int*)     (scratch + 143921152);           //           4 B

    hipMemsetAsync(rcount, 0, sizeof(int), stream);

    centroid_rnorm_kernel<<<NP / 4, 256, 0, stream>>>(cent, rnorm);
    convertC_kernel<<<NP * ND / 8 / 256, 256, 0, stream>>>(cent, Cp);
    convertQ_kernel<<<NB * (ND / 8) / 256, 256, 0, stream>>>(query, Qp);
    gemm_top2_kernel<<<4096, 256, 0, stream>>>(Qp, Cp, rnorm, pv1, pi1, pv2);
    merge_kernel<<<NB / 256, 256, 0, stream>>>(pv1, pi1, pv2, assign_out, rlist, rcount);
    refine_kernel<<<128, 256, 0, stream>>>(query, cent, rnorm, rlist, rcount, assign_out);
    scatter_kernel<<<NB / 2, 256, 0, stream>>>(cent, assign_out, ctx, routing);
}